// Round 2
// baseline (391.202 us; speedup 1.0000x reference)
//
#include <hip/hip_runtime.h>

// BackEdgeConv2d: out = x * !(5 <= boxsum7x7(x >= 128/255, reflect-pad) <= 19)
// x: [16, 3, 1024, 1024] fp32.  Pure streaming stencil, HBM-bound.
//
// One wave per (image-channel, 8-row band). Each lane owns 16 contiguous
// columns -> wave covers the full 1024-wide row. Per row: 4x float4 load,
// threshold -> 16-bit mask, neighbor bits via shuffles (bit-reflected at
// lanes 0/63), 16 horizontal 7-sums via popc, byte-packed into 4 u32s,
// vertical 7-row sliding sum in byte-packed u32s with a register ring.
// No LDS, no barriers.
//
// BH=8 (was 32): 6144 waves = 24/CU. R1 showed 6 waves/CU -> only 35% HBM
// (latency-bound, occupancy 16%); halo re-reads are L3-absorbed (fetch was
// 1.05x ideal at BH=32), so the 1.75x halo factor costs cache reads, not HBM.

constexpr int H = 1024;
constexpr int W = 1024;
constexpr int BH = 8;            // rows per band (per wave)
constexpr int NBANDS = H / BH;   // 128
constexpr int STEPS = BH + 6;    // 14 stencil rows per band (3 halo each side)

__global__ __launch_bounds__(64)
void backedge_kernel(const float* __restrict__ x, float* __restrict__ out) {
    const int lane = threadIdx.x;            // 0..63
    const int band = blockIdx.x;             // 0..127
    const int n    = blockIdx.y;             // 0..47 (B*C)
    const int r0   = band * BH;
    const float* __restrict__ xi = x   + (size_t)n * (size_t)(H * W);
    float*       __restrict__ oi = out + (size_t)n * (size_t)(H * W);
    const int col0 = lane * 16;
    const float THR = 128.0f / 255.0f;

    // ring of last 7 rows' packed horizontal sums (4 u32 = 16 byte-lanes)
    unsigned int hring[7][4];
#pragma unroll
    for (int i = 0; i < 7; ++i)
#pragma unroll
        for (int q = 0; q < 4; ++q) hring[i][q] = 0u;
    unsigned int vs[4] = {0u, 0u, 0u, 0u};   // packed vertical sliding sums

#pragma unroll
    for (int s = 0; s < STEPS; ++s) {
        int g = r0 - 3 + s;
        g = (g < 0) ? -g : g;                 // reflect top
        g = (g >= H) ? (2 * H - 2 - g) : g;   // reflect bottom
        const float* rp = xi + (size_t)g * W + col0;
        const float4 a0 = *(const float4*)(rp + 0);
        const float4 a1 = *(const float4*)(rp + 4);
        const float4 a2 = *(const float4*)(rp + 8);
        const float4 a3 = *(const float4*)(rp + 12);

        // 16 threshold bits: bit j <-> column col0 + j
        unsigned int own =
              (unsigned)(a0.x >= THR)        | ((unsigned)(a0.y >= THR) << 1)
            | ((unsigned)(a0.z >= THR) << 2) | ((unsigned)(a0.w >= THR) << 3)
            | ((unsigned)(a1.x >= THR) << 4) | ((unsigned)(a1.y >= THR) << 5)
            | ((unsigned)(a1.z >= THR) << 6) | ((unsigned)(a1.w >= THR) << 7)
            | ((unsigned)(a2.x >= THR) << 8) | ((unsigned)(a2.y >= THR) << 9)
            | ((unsigned)(a2.z >= THR) << 10)| ((unsigned)(a2.w >= THR) << 11)
            | ((unsigned)(a3.x >= THR) << 12)| ((unsigned)(a3.y >= THR) << 13)
            | ((unsigned)(a3.z >= THR) << 14)| ((unsigned)(a3.w >= THR) << 15);

        unsigned int lft = __shfl_up(own, 1);
        unsigned int rgt = __shfl_down(own, 1);
        if (lane == 0) {
            // reflected cols -3,-2,-1 -> cols 3,2,1 at bits 13,14,15
            lft = (((own >> 3) & 1u) << 13) | (((own >> 2) & 1u) << 14)
                | (((own >> 1) & 1u) << 15);
        }
        if (lane == 63) {
            // reflected cols 1024,1025,1026 -> cols 1022,1021,1020 at bits 0,1,2
            rgt = ((own >> 14) & 1u) | (((own >> 13) & 1u) << 1)
                | (((own >> 12) & 1u) << 2);
        }
        // w: bit i <-> column col0 + i - 3  (22 bits used)
        const unsigned int w = (lft >> 13) | (own << 3) | ((rgt & 7u) << 19);

        unsigned int hp[4];
#pragma unroll
        for (int q = 0; q < 4; ++q) {
            unsigned int h0 = __popc((w >> (4 * q + 0)) & 0x7Fu);
            unsigned int h1 = __popc((w >> (4 * q + 1)) & 0x7Fu);
            unsigned int h2 = __popc((w >> (4 * q + 2)) & 0x7Fu);
            unsigned int h3 = __popc((w >> (4 * q + 3)) & 0x7Fu);
            hp[q] = h0 | (h1 << 8) | (h2 << 16) | (h3 << 24);
        }

        // vertical sliding sum: add newest, drop oldest (byte-packed; each
        // byte <= 49 so base-256 digits never carry/borrow in the net result)
#pragma unroll
        for (int q = 0; q < 4; ++q) vs[q] += hp[q] - hring[0][q];
#pragma unroll
        for (int i = 0; i < 6; ++i)
#pragma unroll
            for (int q = 0; q < 4; ++q) hring[i][q] = hring[i + 1][q];
#pragma unroll
        for (int q = 0; q < 4; ++q) hring[6][q] = hp[q];

        if (s >= 6) {
            const int orow = r0 + s - 6;     // output row (center of window)
            const float* xp = xi + (size_t)orow * W + col0;
            float*       op = oi + (size_t)orow * W + col0;
            const float4 b0 = *(const float4*)(xp + 0);
            const float4 b1 = *(const float4*)(xp + 4);
            const float4 b2 = *(const float4*)(xp + 8);
            const float4 b3 = *(const float4*)(xp + 12);
            float4 o0, o1, o2, o3;
            // masked (zeroed) iff 5 <= csum <= 19  <=>  (csum-5) <= 14 unsigned
            o0.x = ((((vs[0]      ) & 0xFFu) - 5u) <= 14u) ? 0.0f : b0.x;
            o0.y = ((((vs[0] >>  8) & 0xFFu) - 5u) <= 14u) ? 0.0f : b0.y;
            o0.z = ((((vs[0] >> 16) & 0xFFu) - 5u) <= 14u) ? 0.0f : b0.z;
            o0.w = ((((vs[0] >> 24)        ) - 5u) <= 14u) ? 0.0f : b0.w;
            o1.x = ((((vs[1]      ) & 0xFFu) - 5u) <= 14u) ? 0.0f : b1.x;
            o1.y = ((((vs[1] >>  8) & 0xFFu) - 5u) <= 14u) ? 0.0f : b1.y;
            o1.z = ((((vs[1] >> 16) & 0xFFu) - 5u) <= 14u) ? 0.0f : b1.z;
            o1.w = ((((vs[1] >> 24)        ) - 5u) <= 14u) ? 0.0f : b1.w;
            o2.x = ((((vs[2]      ) & 0xFFu) - 5u) <= 14u) ? 0.0f : b2.x;
            o2.y = ((((vs[2] >>  8) & 0xFFu) - 5u) <= 14u) ? 0.0f : b2.y;
            o2.z = ((((vs[2] >> 16) & 0xFFu) - 5u) <= 14u) ? 0.0f : b2.z;
            o2.w = ((((vs[2] >> 24)        ) - 5u) <= 14u) ? 0.0f : b2.w;
            o3.x = ((((vs[3]      ) & 0xFFu) - 5u) <= 14u) ? 0.0f : b3.x;
            o3.y = ((((vs[3] >>  8) & 0xFFu) - 5u) <= 14u) ? 0.0f : b3.y;
            o3.z = ((((vs[3] >> 16) & 0xFFu) - 5u) <= 14u) ? 0.0f : b3.z;
            o3.w = ((((vs[3] >> 24)        ) - 5u) <= 14u) ? 0.0f : b3.w;
            *(float4*)(op + 0)  = o0;
            *(float4*)(op + 4)  = o1;
            *(float4*)(op + 8)  = o2;
            *(float4*)(op + 12) = o3;
        }
    }
}

extern "C" void kernel_launch(void* const* d_in, const int* in_sizes, int n_in,
                              void* d_out, int out_size, void* d_ws, size_t ws_size,
                              hipStream_t stream) {
    const float* x = (const float*)d_in[0];
    float* out = (float*)d_out;
    (void)in_sizes; (void)n_in; (void)d_ws; (void)ws_size; (void)out_size;
    dim3 grid(NBANDS, 16 * 3);   // 128 bands x 48 (B*C) = 6144 single-wave blocks
    backedge_kernel<<<grid, dim3(64), 0, stream>>>(x, out);
}

// Round 3
// 360.139 us; speedup vs baseline: 1.0863x; 1.0863x over previous
//
#include <hip/hip_runtime.h>

// BackEdgeConv2d: out = x * !(5 <= boxsum7x7(x >= 128/255, reflect-pad) <= 19)
// x: [16, 3, 1024, 1024] fp32.  Pure streaming stencil, HBM-bound.
//
// R2 lesson: lane-owns-16-contiguous-cols makes every dwordx4 a 64B-strided
// access (64 lines touched/instruction, 16B used each) -> TCP request-rate
// bound + store write-amplification (WRITE grew 197->228 MB). Fix: lane i
// owns one float4 per quarter-row (cols 256q+4i..+3) so every load/store is
// a wave-contiguous 1KB transaction. 256-thread blocks (4 independent waves)
// dodge the ~16 workgroup/CU slot cap that pinned occupancy at 47%.
//
// Per row: 4 coalesced float4 loads -> 16 threshold bits (bit 4q+j =
// col 256q+4i+j), neighbor bits via shfl +/-1 within quarters and fixed-lane
// broadcasts across quarter seams (reflect at the true image edges), 16
// horizontal 7-sums via popc, byte-packed; vertical 7-row sliding sum in
// byte-packed u32s with a register ring. No LDS, no barriers.

constexpr int H = 1024;
constexpr int W = 1024;
constexpr int BH = 8;            // rows per band (per wave)
constexpr int NBANDS = H / BH;   // 128
constexpr int STEPS = BH + 6;    // 14 stencil rows per band

__global__ __launch_bounds__(256)
void backedge_kernel(const float* __restrict__ x, float* __restrict__ out) {
    const int lane = threadIdx.x & 63;
    const int wv   = threadIdx.x >> 6;            // 0..3, independent waves
    const int band = blockIdx.x * 4 + wv;         // 0..127
    const int n    = blockIdx.y;                  // 0..47 (B*C)
    const int r0   = band * BH;
    const float* __restrict__ xi = x   + (size_t)n * (size_t)(H * W);
    float*       __restrict__ oi = out + (size_t)n * (size_t)(H * W);
    const int off = 4 * lane;                     // float offset inside a quarter
    const float THR = 128.0f / 255.0f;

    unsigned int hring[7][4];
#pragma unroll
    for (int i = 0; i < 7; ++i)
#pragma unroll
        for (int q = 0; q < 4; ++q) hring[i][q] = 0u;
    unsigned int vs[4] = {0u, 0u, 0u, 0u};

#pragma unroll
    for (int s = 0; s < STEPS; ++s) {
        int g = r0 - 3 + s;
        g = (g < 0) ? -g : g;                 // reflect top
        g = (g >= H) ? (2 * H - 2 - g) : g;   // reflect bottom
        const float* rp = xi + (size_t)g * W;
        float4 a[4];
#pragma unroll
        for (int q = 0; q < 4; ++q)
            a[q] = *(const float4*)(rp + q * 256 + off);

        // 16 threshold bits: bit 4q+j <-> col 256q + 4*lane + j
        unsigned int m = 0;
#pragma unroll
        for (int q = 0; q < 4; ++q) {
            m |= ((unsigned)(a[q].x >= THR)) << (4 * q + 0);
            m |= ((unsigned)(a[q].y >= THR)) << (4 * q + 1);
            m |= ((unsigned)(a[q].z >= THR)) << (4 * q + 2);
            m |= ((unsigned)(a[q].w >= THR)) << (4 * q + 3);
        }

        const unsigned int up = __shfl_up(m, 1);    // lane i-1's mask
        const unsigned int dn = __shfl_down(m, 1);  // lane i+1's mask
        const unsigned int hi = __shfl(m, 63);      // lane 63 broadcast
        const unsigned int lo = __shfl(m, 0);       // lane 0 broadcast
        // left-neighbor source: quarter q of SL supplies cols 256q+4i-4..-1
        const unsigned int SL = (lane == 0) ? (hi << 4) : up;
        // right-neighbor source: quarter q of SR supplies cols 256q+4i+4..+7
        const unsigned int SR = (lane == 63) ? (lo >> 4) : dn;

        unsigned int hp[4];
#pragma unroll
        for (int q = 0; q < 4; ++q) {
            // w bit k <-> col (256q + 4*lane) + k - 3   (10 bits used)
            unsigned int w = ((SL >> (4 * q + 1)) & 7u)
                           | (((m >> (4 * q)) & 0xFu) << 3)
                           | (((SR >> (4 * q)) & 7u) << 7);
            if (q == 0 && lane == 0) {
                // cols -3,-2,-1 reflect -> cols 3,2,1 (own bits 3,2,1)
                w |= ((m >> 3) & 1u) | (((m >> 2) & 1u) << 1)
                   | (((m >> 1) & 1u) << 2);
            }
            if (q == 3 && lane == 63) {
                // cols 1024,1025,1026 reflect -> 1022,1021,1020 (bits 14,13,12)
                w |= (((m >> 14) & 1u) << 7) | (((m >> 13) & 1u) << 8)
                   | (((m >> 12) & 1u) << 9);
            }
            const unsigned int h0 = __popc((w >> 0) & 0x7Fu);
            const unsigned int h1 = __popc((w >> 1) & 0x7Fu);
            const unsigned int h2 = __popc((w >> 2) & 0x7Fu);
            const unsigned int h3 = __popc((w >> 3) & 0x7Fu);
            hp[q] = h0 | (h1 << 8) | (h2 << 16) | (h3 << 24);
        }

        // vertical sliding sum (byte-packed; digits <= 49, never carry)
#pragma unroll
        for (int q = 0; q < 4; ++q) vs[q] += hp[q] - hring[0][q];
#pragma unroll
        for (int i = 0; i < 6; ++i)
#pragma unroll
            for (int q = 0; q < 4; ++q) hring[i][q] = hring[i + 1][q];
#pragma unroll
        for (int q = 0; q < 4; ++q) hring[6][q] = hp[q];

        if (s >= 6) {
            const int orow = r0 + s - 6;
            const float* xp = xi + (size_t)orow * W;
            float*       op = oi + (size_t)orow * W;
#pragma unroll
            for (int q = 0; q < 4; ++q) {
                const float4 b = *(const float4*)(xp + q * 256 + off);
                const unsigned int v = vs[q];
                float4 o;
                // zeroed iff 5 <= csum <= 19  <=>  (csum-5) <= 14 unsigned
                o.x = ((((v      ) & 0xFFu) - 5u) <= 14u) ? 0.0f : b.x;
                o.y = ((((v >>  8) & 0xFFu) - 5u) <= 14u) ? 0.0f : b.y;
                o.z = ((((v >> 16) & 0xFFu) - 5u) <= 14u) ? 0.0f : b.z;
                o.w = ((((v >> 24)        ) - 5u) <= 14u) ? 0.0f : b.w;
                *(float4*)(op + q * 256 + off) = o;
            }
        }
    }
}

extern "C" void kernel_launch(void* const* d_in, const int* in_sizes, int n_in,
                              void* d_out, int out_size, void* d_ws, size_t ws_size,
                              hipStream_t stream) {
    const float* x = (const float*)d_in[0];
    float* out = (float*)d_out;
    (void)in_sizes; (void)n_in; (void)d_ws; (void)ws_size; (void)out_size;
    dim3 grid(NBANDS / 4, 16 * 3);   // 32 x 48 blocks of 256 (4 waves/block)
    backedge_kernel<<<grid, dim3(256), 0, stream>>>(x, out);
}